// Round 7
// baseline (342.747 us; speedup 1.0000x reference)
//
#include <hip/hip_runtime.h>
#include <math.h>

typedef unsigned short u16;
typedef __attribute__((ext_vector_type(8))) short bf16x8;
typedef __attribute__((ext_vector_type(4))) float f32x4;
typedef __attribute__((ext_vector_type(4))) unsigned short u16x4;
typedef __attribute__((ext_vector_type(8))) unsigned short u16x8;

constexpr int Sq = 2048, Dm = 1024, Hh = 16, DH = 64;
constexpr int NT = 4096;                 // tokens (B*S)
constexpr float SEXP = 0.125f * 1.44269504f;   // scale * log2(e), folded into Q

#if __has_builtin(__builtin_amdgcn_exp2f)
#define EXP2(x) __builtin_amdgcn_exp2f(x)
#else
#define EXP2(x) exp2f(x)
#endif

__device__ __forceinline__ u16 f2bf(float f) {
    unsigned u = __float_as_uint(f);
    return (u16)((u + 0x7FFF + ((u >> 16) & 1)) >> 16);
}

// async global->LDS, 16B per lane; LDS base is wave-uniform, HW adds lane*16
__device__ __forceinline__ void async16(u16* lds, const u16* g) {
    __builtin_amdgcn_global_load_lds(
        (const __attribute__((address_space(1))) unsigned int*)g,
        (__attribute__((address_space(3))) unsigned int*)lds, 16, 0, 0);
}

__device__ __forceinline__ float lam_of(const int* lidx, const float* lamp) {
    float lf = (float)lidx[0];
    float init = 0.8f - 0.6f * __expf(-0.3f * fmaxf(lf - 1.0f, 0.0f));
    return fminf(fmaxf(init * lamp[0], 0.1f), 0.9f);
}

// ---------------------------------------------------------------------------
// 64x128 MFMA GEMM mainloop (wfull / out)
// ---------------------------------------------------------------------------
__device__ __forceinline__ void gemm_tile_64(
    const u16* __restrict__ A, const u16* __restrict__ Bt, int K,
    int aRow0, int bCol0, u16* As, u16* Bs, f32x4 acc[2][4])
{
    const int tid = threadIdx.x;
    const int w = tid >> 6, lane = tid & 63;
    const int ln = lane & 15, quad = lane >> 4;
    const int wm = (w >> 1) * 32, wn = (w & 1) * 64;
    const int l3 = lane & 7, lr8 = lane >> 3;

    for (int kt = 0; kt < K; kt += 64) {
        __syncthreads();
        #pragma unroll
        for (int c0 = 0; c0 < 2; ++c0) {
            int c = w * 2 + c0;
            int lr = c * 8 + lr8;
            int sc = l3 ^ (lr & 7);
            async16(As + c * 512, A + (size_t)(aRow0 + lr) * K + kt + sc * 8);
        }
        #pragma unroll
        for (int c0 = 0; c0 < 4; ++c0) {
            int c = w * 4 + c0;
            int lr = c * 8 + lr8;
            int sc = l3 ^ (lr & 7);
            async16(Bs + c * 512, Bt + (size_t)(bCol0 + lr) * K + kt + sc * 8);
        }
        __syncthreads();
        #pragma unroll
        for (int kc = 0; kc < 2; ++kc) {
            bf16x8 af[2], bfr[4];
            #pragma unroll
            for (int mt = 0; mt < 2; ++mt)
                af[mt] = *(const bf16x8*)(As + (wm + mt * 16 + ln) * 64 +
                                          (((kc * 4 + quad) ^ (ln & 7)) * 8));
            #pragma unroll
            for (int nt = 0; nt < 4; ++nt)
                bfr[nt] = *(const bf16x8*)(Bs + (wn + nt * 16 + ln) * 64 +
                                           (((kc * 4 + quad) ^ (ln & 7)) * 8));
            #pragma unroll
            for (int mt = 0; mt < 2; ++mt)
                #pragma unroll
                for (int nt = 0; nt < 4; ++nt)
                    acc[mt][nt] = __builtin_amdgcn_mfma_f32_16x16x32_bf16(
                        af[mt], bfr[nt], acc[mt][nt], 0, 0, 0);
        }
    }
}

// ---------------------------------------------------------------------------
__global__ __launch_bounds__(256)
void convert_x(const float* __restrict__ x, u16* __restrict__ xb)
{
    int i = (blockIdx.x * 256 + threadIdx.x) * 4;
    float4 v = *(const float4*)(x + i);
    u16x4 o;
    o.x = f2bf(v.x); o.y = f2bf(v.y); o.z = f2bf(v.z); o.w = f2bf(v.w);
    *(u16x4*)(xb + i) = o;
}

// ---------------------------------------------------------------------------
// Weight transpose-convert: 7 slices (6 QKV weights + Wp -> Wpt)
// ---------------------------------------------------------------------------
struct TcP { const float* src[7]; u16* dst[7]; };

__global__ __launch_bounds__(256)
void wconv(TcP p)
{
    __shared__ float t[64][65];
    const int z = blockIdx.z;
    const float* __restrict__ src = p.src[z];
    u16* __restrict__ dst = p.dst[z];
    const int kb = blockIdx.y * 64, nb = blockIdx.x * 64;
    const int tid = threadIdx.x;
    {
        int r = tid >> 2, cs = (tid & 3) * 16;
        #pragma unroll
        for (int j4 = 0; j4 < 16; j4 += 4) {
            float4 v = *(const float4*)&src[(size_t)(kb + r) * 1024 + nb + cs + j4];
            t[r][cs + j4 + 0] = v.x; t[r][cs + j4 + 1] = v.y;
            t[r][cs + j4 + 2] = v.z; t[r][cs + j4 + 3] = v.w;
        }
    }
    __syncthreads();
    {
        int n = tid >> 2, ks = (tid & 3) * 16;
        u16x8 a, b;
        #pragma unroll
        for (int j = 0; j < 8; ++j) a[j] = f2bf(t[ks + j][n]);
        #pragma unroll
        for (int j = 0; j < 8; ++j) b[j] = f2bf(t[ks + 8 + j][n]);
        u16* o = &dst[(size_t)(nb + n) * 1024 + kb + ks];
        *(u16x8*)o = a;
        *(u16x8*)(o + 8) = b;
    }
}

// ---------------------------------------------------------------------------
// Acat build: rows 0..1023 = bf16(Wo1), rows 1024..2047 = bf16(-lam*Wo2),
// row 2048 = bf16(bo1 - lam*bo2)
// ---------------------------------------------------------------------------
__global__ __launch_bounds__(256)
void woconv(const float* __restrict__ Wo1, const float* __restrict__ Wo2,
            const float* __restrict__ bo1, const float* __restrict__ bo2,
            const int* __restrict__ lidx, const float* __restrict__ lamp,
            u16* __restrict__ Acat)
{
    const float lam = lam_of(lidx, lamp);
    int i = (blockIdx.x * 256 + threadIdx.x) * 4;
    float4 v;
    if (i < 1048576) {
        v = *(const float4*)(Wo1 + i);
    } else if (i < 2097152) {
        v = *(const float4*)(Wo2 + (i - 1048576));
        v.x *= -lam; v.y *= -lam; v.z *= -lam; v.w *= -lam;
    } else {
        int c = i - 2097152;
        float4 a = *(const float4*)(bo1 + c);
        float4 b = *(const float4*)(bo2 + c);
        v.x = a.x - lam * b.x; v.y = a.y - lam * b.y;
        v.z = a.z - lam * b.z; v.w = a.w - lam * b.w;
    }
    u16x4 o;
    o.x = f2bf(v.x); o.y = f2bf(v.y); o.z = f2bf(v.z); o.w = f2bf(v.w);
    *(u16x4*)(Acat + i) = o;
}

// ---------------------------------------------------------------------------
// Wfull GEMM: Acat[2112x1024] @ Wpt^T -> Wfull_bt[n][m] bf16 (m<2048);
// row m==2048 -> bfull[n] = acc + bp[n]
// ---------------------------------------------------------------------------
__global__ __launch_bounds__(256, 4)
void wfull_mfma(const u16* __restrict__ Acat, const u16* __restrict__ Wpt,
                const float* __restrict__ bp, u16* __restrict__ Wfull_bt,
                float* __restrict__ bfull)
{
    __shared__ u16 As[64 * 64], Bs[128 * 64];
    const int aRow0 = blockIdx.y * 64, nCol0 = blockIdx.x * 128;
    f32x4 acc[2][4] = {};
    gemm_tile_64(Acat, Wpt, 1024, aRow0, nCol0, As, Bs, acc);

    const int tid = threadIdx.x, w = tid >> 6, lane = tid & 63;
    const int ln = lane & 15, quad = lane >> 4;
    const int wm = (w >> 1) * 32, wn = (w & 1) * 64;
    #pragma unroll
    for (int mt = 0; mt < 2; ++mt) {
        #pragma unroll
        for (int nt = 0; nt < 4; ++nt) {
            int gn = nCol0 + wn + nt * 16 + ln;
            #pragma unroll
            for (int r = 0; r < 4; ++r) {
                int gm = aRow0 + wm + mt * 16 + quad * 4 + r;
                if (gm < 2048)
                    Wfull_bt[(size_t)gn * 2048 + gm] = f2bf(acc[mt][nt][r]);
                else if (gm == 2048)
                    bfull[gn] = acc[mt][nt][r] + bp[gn];
            }
        }
    }
}

// ---------------------------------------------------------------------------
// QKV projection, z-fused 128x256 tile: xb[4096][1024] @ Wt_all[6144][1024]^T.
// 256-col tile never crosses a z boundary (1024 % 256 == 0).
// Q -> [bh][s][64] pre-scaled by SEXP;  K,V -> MFMA-frag order.
// ---------------------------------------------------------------------------
struct QkvP { const float* bias[6]; u16* out[6]; };

__global__ __launch_bounds__(256, 2)
void qkv_mfma(const u16* __restrict__ xb, const u16* __restrict__ Wt_all, QkvP p)
{
    __shared__ u16 As[128 * 64], Bs[256 * 64];
    const int nCol0 = blockIdx.x * 256;
    const int aRow0 = blockIdx.y * 128;
    const int z = nCol0 >> 10;
    const int type = (z < 3) ? z : z - 3;   // 0=q 1=k 2=v

    const int tid = threadIdx.x, w = tid >> 6, lane = tid & 63;
    const int ln = lane & 15, quad = lane >> 4;
    const int wm = (w >> 1) * 64, wn = (w & 1) * 128;
    const int l3 = lane & 7, lr8 = lane >> 3;

    f32x4 acc[4][8] = {};

    for (int kt = 0; kt < 1024; kt += 64) {
        __syncthreads();
        #pragma unroll
        for (int c0 = 0; c0 < 4; ++c0) {            // A: 16 chunks
            int c = w * 4 + c0;
            int lr = c * 8 + lr8;
            int sc = l3 ^ (lr & 7);
            async16(As + c * 512, xb + (size_t)(aRow0 + lr) * 1024 + kt + sc * 8);
        }
        #pragma unroll
        for (int c0 = 0; c0 < 8; ++c0) {            // B: 32 chunks
            int c = w * 8 + c0;
            int lr = c * 8 + lr8;
            int sc = l3 ^ (lr & 7);
            async16(Bs + c * 512,
                    Wt_all + (size_t)(nCol0 + lr) * 1024 + kt + sc * 8);
        }
        __syncthreads();
        #pragma unroll
        for (int kc = 0; kc < 2; ++kc) {
            bf16x8 af[4], bfr[8];
            #pragma unroll
            for (int mt = 0; mt < 4; ++mt)
                af[mt] = *(const bf16x8*)(As + (wm + mt * 16 + ln) * 64 +
                                          (((kc * 4 + quad) ^ (ln & 7)) * 8));
            #pragma unroll
            for (int nt = 0; nt < 8; ++nt)
                bfr[nt] = *(const bf16x8*)(Bs + (wn + nt * 16 + ln) * 64 +
                                           (((kc * 4 + quad) ^ (ln & 7)) * 8));
            #pragma unroll
            for (int mt = 0; mt < 4; ++mt)
                #pragma unroll
                for (int nt = 0; nt < 8; ++nt)
                    acc[mt][nt] = __builtin_amdgcn_mfma_f32_16x16x32_bf16(
                        af[mt], bfr[nt], acc[mt][nt], 0, 0, 0);
        }
    }

    const float* __restrict__ bias = p.bias[z];
    u16* __restrict__ out = p.out[z];
    #pragma unroll
    for (int mt = 0; mt < 4; ++mt) {
        #pragma unroll
        for (int nt = 0; nt < 8; ++nt) {
            int col = (nCol0 + wn + nt * 16 + ln) & 1023;
            int h = col >> 6, dh = col & 63;
            float bv = bias[col];
            #pragma unroll
            for (int r = 0; r < 4; ++r) {
                int gm = aRow0 + wm + mt * 16 + quad * 4 + r;
                int b = gm >> 11, s = gm & (Sq - 1);
                size_t bh = (size_t)(b * Hh + h);
                float fv = acc[mt][nt][r] + bv;
                size_t idx;
                u16 val;
                if (type == 0) {
                    val = f2bf(fv * SEXP);
                    idx = bh * 131072 + (size_t)s * 64 + dh;
                } else if (type == 1) {
                    val = f2bf(fv);
                    idx = bh * 131072 + (size_t)(s >> 5) * 2048 +
                          (size_t)((dh >> 5) * 2 + ((s >> 4) & 1)) * 512 +
                          (size_t)(((dh >> 3) & 3) * 16 + (s & 15)) * 8 + (dh & 7);
                } else {
                    val = f2bf(fv);
                    int kidx = ((s & 15) * 2) + ((s >> 4) & 1);
                    idx = bh * 131072 + (size_t)(s >> 5) * 2048 +
                          (size_t)(dh >> 4) * 512 +
                          (size_t)((kidx >> 3) * 16 + (dh & 15)) * 8 + (kidx & 7);
                }
                out[idx] = val;
            }
        }
    }
}

// ---------------------------------------------------------------------------
// Flash attention, pipelined P (lag-1).  Wave = 32 q-rows x all 2048 keys.
// step(kt): load K(kt), V(kt-1); S(kt) -> exp/pack -> write P(kt) to Pw;
// read P(kt-1) from Pr -> PV + l-MFMA.  Chain MFMA->exp->ds_write->ds_read
// is broken across iterations.
// ---------------------------------------------------------------------------
__device__ __forceinline__ void attn_step(
    int kt, const u16* kbase, const u16* vbase, char* Pw, char* Pr,
    const bf16x8 qf[2][2], bf16x8 ones,
    f32x4 oacc[2][4], f32x4 lacc[2], int ln, int quad)
{
    const f32x4 zero4 = {0.f, 0.f, 0.f, 0.f};
    const u16* kp = kbase + (size_t)kt * 2048;
    const u16* vp = vbase + (size_t)(kt - 1) * 2048;

    bf16x8 kfr[2][2], vfr[4];
    #pragma unroll
    for (int kc = 0; kc < 2; ++kc)
        #pragma unroll
        for (int nt = 0; nt < 2; ++nt)
            kfr[nt][kc] = *(const bf16x8*)(kp + (kc * 2 + nt) * 512);
    #pragma unroll
    for (int dt = 0; dt < 4; ++dt)
        vfr[dt] = *(const bf16x8*)(vp + dt * 512);

    f32x4 sacc[2][2];
    #pragma unroll
    for (int mt = 0; mt < 2; ++mt)
        #pragma unroll
        for (int nt = 0; nt < 2; ++nt)
            sacc[mt][nt] = __builtin_amdgcn_mfma_f32_16x16x32_bf16(
                qf[mt][0], kfr[nt][0], zero4, 0, 0, 0);
    #pragma unroll
    for (int mt = 0; mt < 2; ++mt)
        #pragma unroll
        for (int nt = 0; nt < 2; ++nt)
            sacc[mt][nt] = __builtin_amdgcn_mfma_f32_16x16x32_bf16(
                qf[mt][1], kfr[nt][1], sacc[mt][nt], 0, 0, 0);

    #pragma unroll
    for (int mt = 0; mt < 2; ++mt) {
        #pragma unroll
        for (int r = 0; r < 4; ++r) {
            float p0 = EXP2(sacc[mt][0][r]);
            float p1 = EXP2(sacc[mt][1][r]);
            unsigned a  = __float_as_uint(p0) + 0x8000u;
            unsigned b2 = __float_as_uint(p1) + 0x8000u;
            unsigned pk = __builtin_amdgcn_perm(b2, a, 0x07060302);
            int row = mt * 16 + quad * 4 + r;
            *(unsigned*)(Pw + row * 80 + (((ln >> 2) ^ r) << 4) +
                         ((ln & 3) << 2)) = pk;
        }
    }

    #pragma unroll
    for (int mt = 0; mt < 2; ++mt) {
        bf16x8 pf = *(const bf16x8*)(Pr + (mt * 16 + ln) * 80 +
                                     ((quad ^ (ln & 3)) << 4));
        lacc[mt] = __builtin_amdgcn_mfma_f32_16x16x32_bf16(
            pf, ones, lacc[mt], 0, 0, 0);
        #pragma unroll
        for (int dt = 0; dt < 4; ++dt)
            oacc[mt][dt] = __builtin_amdgcn_mfma_f32_16x16x32_bf16(
                pf, vfr[dt], oacc[mt][dt], 0, 0, 0);
    }
}

__global__ __launch_bounds__(256, 3)
void attn_mfma(const u16* __restrict__ q1, const u16* __restrict__ kf1,
               const u16* __restrict__ vf1,
               const u16* __restrict__ q2, const u16* __restrict__ kf2,
               const u16* __restrict__ vf2, u16* __restrict__ ocat)
{
    __shared__ __align__(16) char smem[20480];   // per wave: 2 P bufs x 2560 B

    const int bh = blockIdx.x, qblk = blockIdx.y, br = blockIdx.z;
    const u16* __restrict__ q  = br ? q2  : q1;
    const u16* __restrict__ kf = br ? kf2 : kf1;
    const u16* __restrict__ vf = br ? vf2 : vf1;

    const int tid = threadIdx.x, w = tid >> 6, lane = tid & 63;
    const int ln = lane & 15, quad = lane >> 4;
    char* P0 = smem + w * 5120;
    char* P1 = P0 + 2560;

    const u16* qbase = q + (size_t)bh * 131072 +
                       (size_t)(qblk * 128 + w * 32) * 64;
    bf16x8 qf[2][2];
    #pragma unroll
    for (int mt = 0; mt < 2; ++mt)
        #pragma unroll
        for (int kc = 0; kc < 2; ++kc)
            qf[mt][kc] = *(const bf16x8*)(qbase + (mt * 16 + ln) * 64 +
                                          kc * 32 + quad * 8);

    bf16x8 ones;
    #pragma unroll
    for (int j = 0; j < 8; ++j) ones[j] = (short)0x3F80;
    const f32x4 zero4 = {0.f, 0.f, 0.f, 0.f};

    f32x4 oacc[2][4] = {};
    f32x4 lacc[2] = {};

    const u16* kbase = kf + (size_t)bh * 131072 + lane * 8;
    const u16* vbase = vf + (size_t)bh * 131072 + lane * 8;

    // ---- prologue kt=0: S(0) -> P0 (no PV yet) ----
    {
        bf16x8 kfr[2][2];
        #pragma unroll
        for (int kc = 0; kc < 2; ++kc)
            #pragma unroll
            for (int nt = 0; nt < 2; ++nt)
                kfr[nt][kc] = *(const bf16x8*)(kbase + (kc * 2 + nt) * 512);
        f32x4 sacc[2][2];
        #pragma unroll
        for (int mt = 0; mt < 2; ++mt)
            #pragma unroll
            for (int nt = 0; nt < 2; ++nt)
                sacc[mt][nt] = __builtin_amdgcn_mfma_f32_16x16x32_bf16(
                    qf[mt][0], kfr[nt][0], zero4, 0, 0, 0);
        #pragma unroll
        for (int mt = 0; mt < 2; ++mt)
            #pragma unroll
            for (int nt = 0; nt < 2; ++nt)
                sacc[mt][nt] = __builtin_amdgcn_mfma_f32_16x16x32_bf16(
                    qf[mt][1], kfr[nt][1], sacc[mt][nt], 0, 0, 0);
        #pragma unroll
        for (int mt = 0; mt < 2; ++mt) {
            #pragma unroll
            for (int r = 0; r < 4; ++r) {
                float p0 = EXP2(sacc[mt][0][r]);
                float p1 = EXP2(sacc[mt][1][r]);
                unsigned a  = __float_as_uint(p0) + 0x8000u;
                unsigned b2 = __float_as_uint(p1) + 0x8000u;
                unsigned pk = __builtin_amdgcn_perm(b2, a, 0x07060302);
                int row = mt * 16 + quad * 4 + r;
                *(unsigned*)(P0 + row * 80 + (((ln >> 2) ^ r) << 4) +
                             ((ln & 3) << 2)) = pk;
            }
        }
    }

    // ---- main: kt = 1..62 in parity pairs, then kt=63 ----
    for (int it = 0; it < 31; ++it) {
        attn_step(2 * it + 1, kbase, vbase, P1, P0, qf, ones, oacc, lacc, ln, quad);
        attn_step(2 * it + 2, kbase, vbase, P0, P1, qf, ones, oacc, lacc, ln, quad);
        __builtin_amdgcn_s_barrier();   // lockstep only
    }
    attn_step(63, kbase, vbase, P1, P0, qf, ones, oacc, lacc, ln, quad);

    // ---- epilogue PV for kt=63 ----
    {
        const u16* vp = vbase + (size_t)63 * 2048;
        bf16x8 vfr[4];
        #pragma unroll
        for (int dt = 0; dt < 4; ++dt)
            vfr[dt] = *(const bf16x8*)(vp + dt * 512);
        #pragma unroll
        for (int mt = 0; mt < 2; ++mt) {
            bf16x8 pf = *(const bf16x8*)(P1 + (mt * 16 + ln) * 80 +
                                         ((quad ^ (ln & 3)) << 4));
            lacc[mt] = __builtin_amdgcn_mfma_f32_16x16x32_bf16(
                pf, ones, lacc[mt], 0, 0, 0);
            #pragma unroll
            for (int dt = 0; dt < 4; ++dt)
                oacc[mt][dt] = __builtin_amdgcn_mfma_f32_16x16x32_bf16(
                    pf, vfr[dt], oacc[mt][dt], 0, 0, 0);
        }
    }

    // normalize + store
    const int b = bh >> 4, h = bh & 15;
    #pragma unroll
    for (int mt = 0; mt < 2; ++mt) {
        #pragma unroll
        for (int r = 0; r < 4; ++r) {
            float inv = 1.0f / lacc[mt][r];
            int s = qblk * 128 + w * 32 + mt * 16 + quad * 4 + r;
            size_t rowb = (size_t)(b * Sq + s) * 2048 + br * 1024 + h * 64;
            #pragma unroll
            for (int dt = 0; dt < 4; ++dt)
                ocat[rowb + dt * 16 + ln] = f2bf(oacc[mt][dt][r] * inv);
        }
    }
}

// ---------------------------------------------------------------------------
// Fused output: out = ocat[4096][2048] @ Wfull_bt^T + bfull   (fp32 out)
// ---------------------------------------------------------------------------
__global__ __launch_bounds__(256, 4)
void out_mfma(const u16* __restrict__ ocat, const u16* __restrict__ Wfull_bt,
              const float* __restrict__ bfull, float* __restrict__ outb)
{
    __shared__ u16 As[64 * 64], Bs[128 * 64];
    const int aRow0 = blockIdx.y * 64, nCol0 = blockIdx.x * 128;
    f32x4 acc[2][4] = {};
    gemm_tile_64(ocat, Wfull_bt, 2048, aRow0, nCol0, As, Bs, acc);

    const int tid = threadIdx.x, w = tid >> 6, lane = tid & 63;
    const int ln = lane & 15, quad = lane >> 4;
    const int wm = (w >> 1) * 32, wn = (w & 1) * 64;
    #pragma unroll
    for (int mt = 0; mt < 2; ++mt) {
        #pragma unroll
        for (int nt = 0; nt < 4; ++nt) {
            int gn = nCol0 + wn + nt * 16 + ln;
            float bv = bfull[gn];
            #pragma unroll
            for (int r = 0; r < 4; ++r) {
                int gm = aRow0 + wm + mt * 16 + quad * 4 + r;
                outb[(size_t)gm * 1024 + gn] = acc[mt][nt][r] + bv;
            }
        }
    }
}

// ---------------------------------------------------------------------------
extern "C" void kernel_launch(void* const* d_in, const int* in_sizes, int n_in,
                              void* d_out, int out_size, void* d_ws, size_t ws_size,
                              hipStream_t stream)
{
    const float* x    = (const float*)d_in[0];
    const int*   lidx = (const int*)  d_in[1];
    const float* lamp = (const float*)d_in[2];
    const float* Wq1  = (const float*)d_in[3];
    const float* Wk1  = (const float*)d_in[4];
    const float* Wv1  = (const float*)d_in[5];
    const float* Wo1  = (const float*)d_in[6];
    const float* bq1  = (const float*)d_in[7];
    const float* bk1  = (const float*)d_in[8];
    const float* bv1  = (const float*)d_in[9];
    const float* bo1  = (const float*)d_in[10];
    const float* Wq2  = (const float*)d_in[11];
    const float* Wk2  = (const float*)d_in[12];
    const float* Wv2  = (const float*)d_in[13];
    const float* Wo2  = (const float*)d_in[14];
    const float* bq2  = (const float*)d_in[15];
    const float* bk2  = (const float*)d_in[16];
    const float* bv2  = (const float*)d_in[17];
    const float* bo2  = (const float*)d_in[18];
    const float* Wp   = (const float*)d_in[19];
    const float* bp   = (const float*)d_in[20];

    char* wsb = (char*)d_ws;
    const size_t MB = 1 << 20;
    u16* xb    = (u16*)(wsb + 0 * MB);          // 8 MB
    u16* Wt0   = (u16*)(wsb + 8 * MB);          // 6 x 2 MB = Wt_all[6144][1024]
    u16* Wpt   = (u16*)(wsb + 20 * MB);         // 2 MB
    u16* Acat  = (u16*)(wsb + 22 * MB);         // 4.125 MB
    u16* Wfull = (u16*)(wsb + 27 * MB);         // 4 MB
    float* bfull = (float*)(wsb + 31 * MB);     // 4 KB
    u16* qb1   = (u16*)(wsb + 32 * MB);         // 8 MB each
    u16* kb1   = (u16*)(wsb + 40 * MB);
    u16* vb1   = (u16*)(wsb + 48 * MB);
    u16* qb2   = (u16*)(wsb + 56 * MB);
    u16* kb2   = (u16*)(wsb + 64 * MB);
    u16* vb2   = (u16*)(wsb + 72 * MB);
    u16* ocat  = (u16*)(wsb + 80 * MB);         // 16 MB

    convert_x<<<dim3(NT * Dm / 1024), dim3(256), 0, stream>>>(x, xb);

    TcP tp;
    const float* wsrc[7] = {Wq1, Wk1, Wv1, Wq2, Wk2, Wv2, Wp};
    for (int i = 0; i < 7; ++i) tp.src[i] = wsrc[i];
    for (int i = 0; i < 6; ++i) tp.dst[i] = Wt0 + (size_t)i * 1048576;
    tp.dst[6] = Wpt;
    wconv<<<dim3(16, 16, 7), dim3(256), 0, stream>>>(tp);

    woconv<<<dim3(2049), dim3(256), 0, stream>>>(
        Wo1, Wo2, bo1, bo2, lidx, lamp, Acat);

    wfull_mfma<<<dim3(8, 33), dim3(256), 0, stream>>>(
        Acat, Wpt, bp, Wfull, bfull);

    QkvP qp;
    qp.bias[0] = bq1; qp.out[0] = qb1;
    qp.bias[1] = bk1; qp.out[1] = kb1;
    qp.bias[2] = bv1; qp.out[2] = vb1;
    qp.bias[3] = bq2; qp.out[3] = qb2;
    qp.bias[4] = bk2; qp.out[4] = kb2;
    qp.bias[5] = bv2; qp.out[5] = vb2;
    qkv_mfma<<<dim3(24, 32), dim3(256), 0, stream>>>(xb, Wt0, qp);

    attn_mfma<<<dim3(32, 16, 2), dim3(256), 0, stream>>>(
        qb1, kb1, vb1, qb2, kb2, vb2, ocat);

    out_mfma<<<dim3(8, 64), dim3(256), 0, stream>>>(
        ocat, Wfull, bfull, (float*)d_out);
}